// Round 15
// baseline (89.984 us; speedup 1.0000x reference)
//
#include <hip/hip_runtime.h>

#define DEV __device__ __forceinline__

typedef __attribute__((ext_vector_type(8))) short s16x8;
typedef __attribute__((ext_vector_type(4))) float f32x4;
typedef __attribute__((ext_vector_type(4))) unsigned short u16x4;
typedef __attribute__((ext_vector_type(2))) unsigned int u32x2;

static constexpr int Bb = 4, Nn = 1024, Dd = 1024, Hh = 16, DKk = 64;

DEV unsigned short f2bf(float f) {
    union { float f; unsigned int u; } x; x.f = f;
    unsigned int r = x.u + 0x7FFFu + ((x.u >> 16) & 1u);
    return (unsigned short)(r >> 16);
}

DEV float fexp2(float x) {
#if __has_builtin(__builtin_amdgcn_exp2f)
    return __builtin_amdgcn_exp2f(x);
#else
    return exp2f(x);
#endif
}

DEV void gld16(const void* g, void* l) {
    __builtin_amdgcn_global_load_lds(
        (const __attribute__((address_space(1))) void*)g,
        (__attribute__((address_space(3))) void*)l, 16, 0, 0);
}

// counted-vmcnt wait + barrier (attn): previous tile's 2 loads done, next 2 in flight
DEV void wait_vm2_barrier() {
    __builtin_amdgcn_sched_barrier(0);
    asm volatile("s_waitcnt vmcnt(2)" ::: "memory");
    __builtin_amdgcn_sched_barrier(0);
    __builtin_amdgcn_s_barrier();
}

// T1 XCD-chunked bijective block remap (nwg % 8 == 0): hardware round-robins
// dispatch index L to XCD L%8; remapped tile id gives each XCD a CONTIGUOUS
// chunk of tiles so shared operand panels stay resident in that XCD's L2.
DEV int xcd_swz(int lin, int nwg) {
    const int chunk = nwg >> 3;
    return (lin & 7) * chunk + (lin >> 3);
}

// ---------------- fp32 -> bf16 pre-cast of x and the four weights; block 4096 decodes mask ----------------
__global__ __launch_bounds__(256) void cast_k(const float* __restrict__ x,
                                              const float* __restrict__ Wq,
                                              const float* __restrict__ Wk,
                                              const float* __restrict__ Wv,
                                              const float* __restrict__ Wo,
                                              const unsigned int* __restrict__ mraw,
                                              unsigned short* __restrict__ xb,
                                              unsigned short* __restrict__ Wqb,
                                              unsigned short* __restrict__ Wkb,
                                              unsigned short* __restrict__ Wvb,
                                              unsigned short* __restrict__ Wob,
                                              int* __restrict__ lengths) {
    if (blockIdx.x == 4096) {
        __shared__ int is_u8;
        const int tid = threadIdx.x;
        if (tid == 0) is_u8 = 0;
        __syncthreads();
        int nz = 0;
        for (int i = tid; i < 1024; i += 256) nz |= (mraw[i] != 0u) ? 1 : 0;
        if (nz) is_u8 = 1;
        __syncthreads();
        const int wv = tid >> 6, lane = tid & 63;
        int cnt = 0;
        if (is_u8) {
            const unsigned char* b8 = (const unsigned char*)mraw;
            for (int n = lane; n < Nn; n += 64) cnt += (b8[wv * Nn + n] == 0) ? 1 : 0;
        } else {
            for (int n = lane; n < Nn; n += 64) cnt += (mraw[wv * Nn + n] == 0u) ? 1 : 0;
        }
#pragma unroll
        for (int off = 32; off; off >>= 1) cnt += __shfl_xor(cnt, off);
        if (lane == 0) lengths[wv] = cnt;
        return;
    }
    const size_t i = ((size_t)blockIdx.x * 256 + threadIdx.x) * 8;
    const float* src;
    unsigned short* dst;
    size_t off;
    const size_t XE = (size_t)4 * 1024 * 1024, WE = (size_t)1024 * 1024;
    if (i < XE) {
        src = x; dst = xb; off = i;
    } else {
        size_t j = i - XE;
        int w = (int)(j >> 20);
        off = j & (WE - 1);
        src = (w == 0) ? Wq : (w == 1) ? Wk : (w == 2) ? Wv : Wo;
        dst = (w == 0) ? Wqb : (w == 1) ? Wkb : (w == 2) ? Wvb : Wob;
    }
    f32x4 a = *(const f32x4*)(src + off);
    f32x4 b = *(const f32x4*)(src + off + 4);
    s16x8 t;
    t[0] = (short)f2bf(a[0]); t[1] = (short)f2bf(a[1]);
    t[2] = (short)f2bf(a[2]); t[3] = (short)f2bf(a[3]);
    t[4] = (short)f2bf(b[0]); t[5] = (short)f2bf(b[1]);
    t[6] = (short)f2bf(b[2]); t[7] = (short)f2bf(b[3]);
    *(s16x8*)(dst + off) = t;
}

// ---------------- 128x128 GEMM K-loop: BK=64, single buffer, XOR-swizzled LDS (round-8 proven) ----------------
DEV void gemm_kloop(const unsigned short* __restrict__ A,
                    const unsigned short* __restrict__ W,
                    char* lA, char* lB, int bm, int bn,
                    int tid, int kstep0, f32x4 (&acc)[4][4]) {
    const int wv = tid >> 6, lane = tid & 63, g = lane >> 4, lr = lane & 15;
    const int wr = wv >> 1, wc = wv & 1;

    const int rbase = wv * 8 + (lane >> 3);
    const int corig = (lane & 7) ^ (lane >> 3);
    const unsigned short* Asrc = A + (size_t)(bm + rbase) * Dd + corig * 8;
    const unsigned short* Bsrc = W + (size_t)(bn + rbase) * Dd + corig * 8;
    const int ldsb = wv * 1024;
    const int xk = (lr & 7);

    int kstep = kstep0;
    for (int it = 0; it < 16; ++it) {
        const int k0 = kstep * 64;
#pragma unroll
        for (int p = 0; p < 4; ++p) {
            gld16(Asrc + (size_t)(p * 32) * Dd + k0, lA + p * 4096 + ldsb);
            gld16(Bsrc + (size_t)(p * 32) * Dd + k0, lB + p * 4096 + ldsb);
        }
        __syncthreads();
#pragma unroll
        for (int s = 0; s < 2; ++s) {
            s16x8 af[4], bf[4];
#pragma unroll
            for (int m = 0; m < 4; ++m)
                af[m] = *(const s16x8*)(lA + (wr * 64 + m * 16 + lr) * 128 + (((s * 4 + g) ^ xk) << 4));
#pragma unroll
            for (int n = 0; n < 4; ++n)
                bf[n] = *(const s16x8*)(lB + (wc * 64 + n * 16 + lr) * 128 + (((s * 4 + g) ^ xk) << 4));
#pragma unroll
            for (int m = 0; m < 4; ++m)
#pragma unroll
                for (int n = 0; n < 4; ++n)
                    acc[m][n] = __builtin_amdgcn_mfma_f32_16x16x32_bf16(af[m], bf[n], acc[m][n], 0, 0, 0);
        }
        __syncthreads();
        kstep = (kstep + 1) & 15;
    }
}

// ---------------- QKV GEMM: z=0 Q row-major (pre-scaled); z=1 K chunk-swizzled; z=2 V^T chunk-swizzled ----------------
__global__ __launch_bounds__(256, 4) void gemm_qkv_k(const unsigned short* __restrict__ xb,
                                                     const unsigned short* __restrict__ Wqb,
                                                     const unsigned short* __restrict__ Wkb,
                                                     const unsigned short* __restrict__ Wvb,
                                                     const float* __restrict__ bq,
                                                     const float* __restrict__ bk,
                                                     const float* __restrict__ bv,
                                                     const int* __restrict__ lengths,
                                                     unsigned short* __restrict__ Qo,
                                                     unsigned short* __restrict__ Ko,
                                                     unsigned short* __restrict__ Vo) {
    __shared__ __align__(16) char lA[128 * 64 * 2];
    __shared__ __align__(16) char lB[128 * 64 * 2];
    // XCD swizzle: 768 tiles, 96/XCD = 3 complete W-panels -> W stays L2-resident
    const int lin = blockIdx.x + 32 * (blockIdx.y + 8 * blockIdx.z);
    const int nl = xcd_swz(lin, 768);
    const int bx = nl & 31, by = (nl >> 5) & 7, z = nl >> 8;
    const int bm = bx * 128, bn = by * 128;
    if (z != 0 && (bm & 1023) >= lengths[bm >> 10]) return;  // fully padded K/V block

    const unsigned short* W = (z == 0) ? Wqb : (z == 1) ? Wkb : Wvb;
    const float* bias = (z == 0) ? bq : (z == 1) ? bk : bv;

    const int tid = threadIdx.x;
    const int wv = tid >> 6, lane = tid & 63, g = lane >> 4, lr = lane & 15;
    const int wr = wv >> 1, wc = wv & 1;
    const int kstep0 = (bx * 5 + by * 3 + z * 7) & 15;

    f32x4 acc[4][4];
#pragma unroll
    for (int m = 0; m < 4; ++m)
#pragma unroll
        for (int n = 0; n < 4; ++n) acc[m][n] = (f32x4){0.f, 0.f, 0.f, 0.f};

    gemm_kloop(xb, W, lA, lB, bm, bn, tid, kstep0, acc);

    const int row0 = bm + wr * 64 + g * 4;
    if (z == 0) {
        const float qs = 0.125f * 1.44269504f;  // dk^-0.5 * log2(e)
#pragma unroll
        for (int m = 0; m < 4; ++m)
#pragma unroll
            for (int n = 0; n < 4; ++n) {
                const int col = bn + wc * 64 + n * 16 + lr;
                const float bv_ = bias[col];
#pragma unroll
                for (int r = 0; r < 4; ++r)
                    Qo[(size_t)(row0 + m * 16 + r) * Dd + col] = f2bf((acc[m][n][r] + bv_) * qs);
            }
    } else if (z == 1) {
        // Kg[((b*H+h)*N + tok)*64 + ((dk>>3)^(tok&7))*8 + (dk&7)]
#pragma unroll
        for (int m = 0; m < 4; ++m)
#pragma unroll
            for (int n = 0; n < 4; ++n) {
                const int col = bn + wc * 64 + n * 16 + lr;
                const int h = col >> 6, dk = col & 63;
                const float bv_ = bias[col];
#pragma unroll
                for (int r = 0; r < 4; ++r) {
                    const int rowg = row0 + m * 16 + r;
                    const int b_ = rowg >> 10, tok = rowg & 1023;
                    size_t idx = ((size_t)(b_ * Hh + h) * Nn + tok) * DKk +
                                 (((dk >> 3) ^ (tok & 7)) << 3) + (dk & 7);
                    Ko[idx] = f2bf(acc[m][n][r] + bv_);
                }
            }
    } else {
        // Vt[((b*H+h)*64 + dk)*N + (tok&~63) + (((tok>>3)&7)^(dk&7))*8 + (tok&7)]
#pragma unroll
        for (int m = 0; m < 4; ++m)
#pragma unroll
            for (int n = 0; n < 4; ++n) {
                const int col = bn + wc * 64 + n * 16 + lr;
                const int h = col >> 6, dk = col & 63;
                const float bv_ = bias[col];
                const int rowg = row0 + m * 16;
                const int b_ = rowg >> 10, tok = rowg & 1023;
                u16x4 t;
#pragma unroll
                for (int r = 0; r < 4; ++r) t[r] = f2bf(acc[m][n][r] + bv_);
                size_t idx = ((size_t)(b_ * Hh + h) * DKk + dk) * Nn + (tok & ~63) +
                             ((((tok >> 3) & 7) ^ (dk & 7)) << 3) + (tok & 7);
                *(u16x4*)(Vo + idx) = t;
            }
    }
}

// ---------------- out projection GEMM: 64x128 tile (512 blocks = 2/CU), BK=64 ----------------
__global__ __launch_bounds__(256, 4) void gemm_out_k(const unsigned short* __restrict__ Ab,
                                                     const unsigned short* __restrict__ Wob,
                                                     const float* __restrict__ bo,
                                                     float* __restrict__ out) {
    __shared__ __align__(16) char lA[64 * 64 * 2];
    __shared__ __align__(16) char lB[128 * 64 * 2];
    const int tid = threadIdx.x;
    const int wv = tid >> 6, lane = tid & 63, g = lane >> 4, lr = lane & 15;
    const int wr = wv >> 1, wc = wv & 1;
    // XCD swizzle: 512 tiles, 64/XCD = 1 complete Wo-panel -> L2-resident
    const int lin = blockIdx.x + 64 * blockIdx.y;
    const int nl = xcd_swz(lin, 512);
    const int bm = (nl & 63) * 64, bn = (nl >> 6) * 128;
    const int kstep0 = (nl * 5) & 15;

    f32x4 acc[2][4];
#pragma unroll
    for (int m = 0; m < 2; ++m)
#pragma unroll
        for (int n = 0; n < 4; ++n) acc[m][n] = (f32x4){0.f, 0.f, 0.f, 0.f};

    const int rbase = wv * 8 + (lane >> 3);
    const int corig = (lane & 7) ^ (lane >> 3);
    const unsigned short* Asrc = Ab + (size_t)(bm + rbase) * Dd + corig * 8;
    const unsigned short* Bsrc = Wob + (size_t)(bn + rbase) * Dd + corig * 8;
    const int ldsb = wv * 1024;
    const int xk = (lr & 7);

    int kstep = kstep0;
    for (int it = 0; it < 16; ++it) {
        const int k0 = kstep * 64;
#pragma unroll
        for (int p = 0; p < 2; ++p)
            gld16(Asrc + (size_t)(p * 32) * Dd + k0, lA + p * 4096 + ldsb);
#pragma unroll
        for (int p = 0; p < 4; ++p)
            gld16(Bsrc + (size_t)(p * 32) * Dd + k0, lB + p * 4096 + ldsb);
        __syncthreads();
#pragma unroll
        for (int s = 0; s < 2; ++s) {
            s16x8 af[2], bf[4];
#pragma unroll
            for (int m = 0; m < 2; ++m)
                af[m] = *(const s16x8*)(lA + (wr * 32 + m * 16 + lr) * 128 + (((s * 4 + g) ^ xk) << 4));
#pragma unroll
            for (int n = 0; n < 4; ++n)
                bf[n] = *(const s16x8*)(lB + (wc * 64 + n * 16 + lr) * 128 + (((s * 4 + g) ^ xk) << 4));
#pragma unroll
            for (int m = 0; m < 2; ++m)
#pragma unroll
                for (int n = 0; n < 4; ++n)
                    acc[m][n] = __builtin_amdgcn_mfma_f32_16x16x32_bf16(af[m], bf[n], acc[m][n], 0, 0, 0);
        }
        __syncthreads();
        kstep = (kstep + 1) & 15;
    }

    const int row0 = bm + wr * 32 + g * 4;
#pragma unroll
    for (int m = 0; m < 2; ++m)
#pragma unroll
        for (int n = 0; n < 4; ++n) {
            const int col = bn + wc * 64 + n * 16 + lr;
            const float bv_ = bo[col];
#pragma unroll
            for (int r = 0; r < 4; ++r)
                out[(size_t)(row0 + m * 16 + r) * Dd + col] = acc[m][n][r] + bv_;
        }
}

// ---------------- fused attention: QBLK=128 (8 waves), swapped QK^T, acc-bias log2 softmax ----------------
__global__ __launch_bounds__(512) void attn_k(const unsigned short* __restrict__ Q,
                                              const unsigned short* __restrict__ Kg,
                                              const unsigned short* __restrict__ Vtg,
                                              const int* __restrict__ lengths,
                                              unsigned short* __restrict__ O) {
    const int tid = threadIdx.x;
    const int wv = tid >> 6, lane = tid & 63, g = lane >> 4, lr = lane & 15;
    // XCD swizzle: 512 tiles, 64/XCD = 8 complete (b,h) groups -> K/V L2-resident
    const int bid = xcd_swz(blockIdx.x, 512);
    const int qt = bid & 7, h = (bid >> 3) & 15, b = bid >> 7;
    const int len = lengths[b];
    const int nt = (len + 63) >> 6;

    __shared__ __align__(16) char Ks[2 * 64 * 128];    // [buf][key][dk], swizzled chunks
    __shared__ __align__(16) char Vs[2 * 64 * 128];    // [buf][dk][key], swizzled chunks
    __shared__ __align__(16) char Ps[8][16 * 128];     // per-wave P [q][key], swizzled chunks

    s16x8 qf[2];
    {
        const int qrow = b * Nn + qt * 128 + wv * 16 + lr;
        const unsigned short* qp = Q + (size_t)qrow * Dd + h * DKk + g * 8;
        qf[0] = *(const s16x8*)qp;
        qf[1] = *(const s16x8*)(qp + 32);
    }

    float m_run = 0.f, l_run = 0.f;
    f32x4 oacc[4];
#pragma unroll
    for (int dt = 0; dt < 4; ++dt) oacc[dt] = (f32x4){0.f, 0.f, 0.f, 0.f};

    const int r0 = tid >> 3, c0 = tid & 7;   // 512 threads cover all 512 chunks/matrix
    const unsigned short* Kbase = Kg + (size_t)(b * Hh + h) * Nn * DKk;
    const unsigned short* Vbase = Vtg + (size_t)(b * Hh + h) * DKk * Nn;

    const int xk16 = (lr & 7) << 4;
    const int shsrc = (lane & 48) | (g * 4);

    // prologue: stage tile 0 into buf 0
    gld16(Kbase + (size_t)r0 * DKk + c0 * 8, Ks + tid * 16);
    gld16(Vbase + (size_t)r0 * Nn + c0 * 8, Vs + tid * 16);

    int cur = 0;
    for (int kt = 0; kt < nt; ++kt) {
        const int kb = kt * 64;
        {
            const int kb2 = (kt + 1 < nt) ? kb + 64 : 0;
            const int nb = (cur ^ 1) * 8192;
            gld16(Kbase + (size_t)(kb2 + r0) * DKk + c0 * 8, Ks + nb + tid * 16);
            gld16(Vbase + (size_t)r0 * Nn + kb2 + c0 * 8, Vs + nb + tid * 16);
        }
        wait_vm2_barrier();  // tile kt resident; tile kt+1's loads stay in flight

        const char* ks_ = Ks + cur * 8192;
        const char* vs_ = Vs + cur * 8192;

        const float nm = -m_run;
        f32x4 sfr[4];
        __builtin_amdgcn_s_setprio(1);
#pragma unroll
        for (int ct = 0; ct < 4; ++ct) {
            f32x4 c = (f32x4){nm, nm, nm, nm};
#pragma unroll
            for (int s = 0; s < 2; ++s) {
                s16x8 kf = *(const s16x8*)(ks_ + (ct * 16 + lr) * 128 + ((((s * 4 + g) << 4)) ^ xk16));
                c = __builtin_amdgcn_mfma_f32_16x16x32_bf16(kf, qf[s], c, 0, 0, 0);
            }
            sfr[ct] = c;
        }
        __builtin_amdgcn_s_setprio(0);

        float mx = -INFINITY;
        if (kb + 64 <= len) {
#pragma unroll
            for (int ct = 0; ct < 4; ++ct)
#pragma unroll
                for (int r = 0; r < 4; ++r) mx = fmaxf(mx, sfr[ct][r]);
        } else {
#pragma unroll
            for (int ct = 0; ct < 4; ++ct) {
                const int kb4 = kb + ct * 16 + g * 4;
#pragma unroll
                for (int r = 0; r < 4; ++r) {
                    const float s_ = (kb4 + r < len) ? sfr[ct][r] : -INFINITY;
                    sfr[ct][r] = s_;
                    mx = fmaxf(mx, s_);
                }
            }
        }
        mx = fmaxf(mx, __shfl_xor(mx, 16));
        mx = fmaxf(mx, __shfl_xor(mx, 32));

        float ls = 0.f;
        if (__any(mx > 8.f)) {
            const float dm = fmaxf(mx, 0.f);
            const float alpha = fexp2(-dm);
            m_run += dm;
            l_run *= alpha;
            float ao[4];
#pragma unroll
            for (int r = 0; r < 4; ++r) ao[r] = __shfl(alpha, shsrc + r);
#pragma unroll
            for (int dt = 0; dt < 4; ++dt)
#pragma unroll
                for (int r = 0; r < 4; ++r) oacc[dt][r] *= ao[r];
#pragma unroll
            for (int ct = 0; ct < 4; ++ct)
#pragma unroll
                for (int r = 0; r < 4; ++r) {
                    const float p = fexp2(sfr[ct][r] - dm);
                    sfr[ct][r] = p;
                    ls += p;
                }
        } else {
#pragma unroll
            for (int ct = 0; ct < 4; ++ct)
#pragma unroll
                for (int r = 0; r < 4; ++r) {
                    const float p = fexp2(sfr[ct][r]);
                    sfr[ct][r] = p;
                    ls += p;
                }
        }
        ls += __shfl_xor(ls, 16);
        ls += __shfl_xor(ls, 32);
        l_run += ls;

#pragma unroll
        for (int ct = 0; ct < 4; ++ct) {
            unsigned int w0, w1;
            asm("v_cvt_pk_bf16_f32 %0, %1, %2" : "=v"(w0) : "v"(sfr[ct][0]), "v"(sfr[ct][1]));
            asm("v_cvt_pk_bf16_f32 %0, %1, %2" : "=v"(w1) : "v"(sfr[ct][2]), "v"(sfr[ct][3]));
            u32x2 wp; wp[0] = w0; wp[1] = w1;
            *(u32x2*)(Ps[wv] + lr * 128 + ((ct * 32 + g * 8) ^ xk16)) = wp;
        }

        __builtin_amdgcn_s_setprio(1);
#pragma unroll
        for (int s = 0; s < 2; ++s) {
            s16x8 pf = *(const s16x8*)(Ps[wv] + lr * 128 + ((((s * 4 + g) << 4)) ^ xk16));
#pragma unroll
            for (int dt = 0; dt < 4; ++dt) {
                s16x8 vf = *(const s16x8*)(vs_ + (dt * 16 + lr) * 128 + ((((s * 4 + g) << 4)) ^ xk16));
                oacc[dt] = __builtin_amdgcn_mfma_f32_16x16x32_bf16(pf, vf, oacc[dt], 0, 0, 0);
            }
        }
        __builtin_amdgcn_s_setprio(0);
        __builtin_amdgcn_s_barrier();
        cur ^= 1;
    }

    float lo[4];
#pragma unroll
    for (int r = 0; r < 4; ++r) lo[r] = __shfl(l_run, shsrc + r);
#pragma unroll
    for (int dt = 0; dt < 4; ++dt) {
        const int col = h * DKk + dt * 16 + lr;
#pragma unroll
        for (int r = 0; r < 4; ++r) {
            const int row = qt * 128 + wv * 16 + g * 4 + r;
            float v = oacc[dt][r] / lo[r];
            O[(size_t)(b * Nn + row) * Dd + col] = f2bf(v);
        }
    }
}

extern "C" void kernel_launch(void* const* d_in, const int* in_sizes, int n_in,
                              void* d_out, int out_size, void* d_ws, size_t ws_size,
                              hipStream_t stream) {
    const float* x  = (const float*)d_in[0];
    const unsigned int* mraw = (const unsigned int*)d_in[1];
    const float* Wq = (const float*)d_in[2];
    const float* bq = (const float*)d_in[3];
    const float* Wk = (const float*)d_in[4];
    const float* bk = (const float*)d_in[5];
    const float* Wv = (const float*)d_in[6];
    const float* bv = (const float*)d_in[7];
    const float* Wo = (const float*)d_in[8];
    const float* bo = (const float*)d_in[9];

    char* ws = (char*)d_ws;
    int* lengths        = (int*)ws;                      ws += 1 << 16;
    unsigned short* xb  = (unsigned short*)ws;           ws += (size_t)Bb * Nn * Dd * 2;
    unsigned short* Wqb = (unsigned short*)ws;           ws += (size_t)Dd * Dd * 2;
    unsigned short* Wkb = (unsigned short*)ws;           ws += (size_t)Dd * Dd * 2;
    unsigned short* Wvb = (unsigned short*)ws;           ws += (size_t)Dd * Dd * 2;
    unsigned short* Wob = (unsigned short*)ws;           ws += (size_t)Dd * Dd * 2;
    unsigned short* Qb  = (unsigned short*)ws;           ws += (size_t)Bb * Nn * Dd * 2;
    unsigned short* Kg  = (unsigned short*)ws;           ws += (size_t)Bb * Nn * Dd * 2;
    unsigned short* Vtg = (unsigned short*)ws;           ws += (size_t)Bb * Nn * Dd * 2;
    unsigned short* Ab  = (unsigned short*)ws;

    cast_k<<<4097, 256, 0, stream>>>(x, Wq, Wk, Wv, Wo, mraw,
                                     xb, Wqb, Wkb, Wvb, Wob, lengths);

    dim3 qkv_grid(Bb * Nn / 128, Dd / 128, 3);
    gemm_qkv_k<<<qkv_grid, 256, 0, stream>>>(xb, Wqb, Wkb, Wvb, bq, bk, bv, lengths,
                                             Qb, Kg, Vtg);

    attn_k<<<Bb * Hh * (Nn / 128), 512, 0, stream>>>(Qb, Kg, Vtg, lengths, Ab);

    dim3 out_grid(Bb * Nn / 64, Dd / 128);
    gemm_out_k<<<out_grid, 256, 0, stream>>>(Ab, Wob, bo, (float*)d_out);
}

// Round 16
// 89.117 us; speedup vs baseline: 1.0097x; 1.0097x over previous
//
#include <hip/hip_runtime.h>

#define DEV __device__ __forceinline__

typedef __attribute__((ext_vector_type(8))) short s16x8;
typedef __attribute__((ext_vector_type(4))) float f32x4;
typedef __attribute__((ext_vector_type(4))) unsigned short u16x4;
typedef __attribute__((ext_vector_type(2))) unsigned int u32x2;

static constexpr int Bb = 4, Nn = 1024, Dd = 1024, Hh = 16, DKk = 64;

DEV unsigned short f2bf(float f) {
    union { float f; unsigned int u; } x; x.f = f;
    unsigned int r = x.u + 0x7FFFu + ((x.u >> 16) & 1u);
    return (unsigned short)(r >> 16);
}

DEV float fexp2(float x) {
#if __has_builtin(__builtin_amdgcn_exp2f)
    return __builtin_amdgcn_exp2f(x);
#else
    return exp2f(x);
#endif
}

DEV void gld16(const void* g, void* l) {
    __builtin_amdgcn_global_load_lds(
        (const __attribute__((address_space(1))) void*)g,
        (__attribute__((address_space(3))) void*)l, 16, 0, 0);
}

// counted-vmcnt wait + barrier (attn): previous tile's 2 loads done, next 2 in flight
DEV void wait_vm2_barrier() {
    __builtin_amdgcn_sched_barrier(0);
    asm volatile("s_waitcnt vmcnt(2)" ::: "memory");
    __builtin_amdgcn_sched_barrier(0);
    __builtin_amdgcn_s_barrier();
}

// ---------------- fp32 -> bf16 pre-cast of x and the four weights; block 4096 decodes mask ----------------
__global__ __launch_bounds__(256) void cast_k(const float* __restrict__ x,
                                              const float* __restrict__ Wq,
                                              const float* __restrict__ Wk,
                                              const float* __restrict__ Wv,
                                              const float* __restrict__ Wo,
                                              const unsigned int* __restrict__ mraw,
                                              unsigned short* __restrict__ xb,
                                              unsigned short* __restrict__ Wqb,
                                              unsigned short* __restrict__ Wkb,
                                              unsigned short* __restrict__ Wvb,
                                              unsigned short* __restrict__ Wob,
                                              int* __restrict__ lengths) {
    if (blockIdx.x == 4096) {
        __shared__ int is_u8;
        const int tid = threadIdx.x;
        if (tid == 0) is_u8 = 0;
        __syncthreads();
        int nz = 0;
        for (int i = tid; i < 1024; i += 256) nz |= (mraw[i] != 0u) ? 1 : 0;
        if (nz) is_u8 = 1;
        __syncthreads();
        const int wv = tid >> 6, lane = tid & 63;
        int cnt = 0;
        if (is_u8) {
            const unsigned char* b8 = (const unsigned char*)mraw;
            for (int n = lane; n < Nn; n += 64) cnt += (b8[wv * Nn + n] == 0) ? 1 : 0;
        } else {
            for (int n = lane; n < Nn; n += 64) cnt += (mraw[wv * Nn + n] == 0u) ? 1 : 0;
        }
#pragma unroll
        for (int off = 32; off; off >>= 1) cnt += __shfl_xor(cnt, off);
        if (lane == 0) lengths[wv] = cnt;
        return;
    }
    const size_t i = ((size_t)blockIdx.x * 256 + threadIdx.x) * 8;
    const float* src;
    unsigned short* dst;
    size_t off;
    const size_t XE = (size_t)4 * 1024 * 1024, WE = (size_t)1024 * 1024;
    if (i < XE) {
        src = x; dst = xb; off = i;
    } else {
        size_t j = i - XE;
        int w = (int)(j >> 20);
        off = j & (WE - 1);
        src = (w == 0) ? Wq : (w == 1) ? Wk : (w == 2) ? Wv : Wo;
        dst = (w == 0) ? Wqb : (w == 1) ? Wkb : (w == 2) ? Wvb : Wob;
    }
    f32x4 a = *(const f32x4*)(src + off);
    f32x4 b = *(const f32x4*)(src + off + 4);
    s16x8 t;
    t[0] = (short)f2bf(a[0]); t[1] = (short)f2bf(a[1]);
    t[2] = (short)f2bf(a[2]); t[3] = (short)f2bf(a[3]);
    t[4] = (short)f2bf(b[0]); t[5] = (short)f2bf(b[1]);
    t[6] = (short)f2bf(b[2]); t[7] = (short)f2bf(b[3]);
    *(s16x8*)(dst + off) = t;
}

// ---------------- 128x128 GEMM K-loop: BK=64, single buffer, XOR-swizzled LDS (round-8 proven) ----------------
DEV void gemm_kloop(const unsigned short* __restrict__ A,
                    const unsigned short* __restrict__ W,
                    char* lA, char* lB, int bm, int bn,
                    int tid, int kstep0, f32x4 (&acc)[4][4]) {
    const int wv = tid >> 6, lane = tid & 63, g = lane >> 4, lr = lane & 15;
    const int wr = wv >> 1, wc = wv & 1;

    const int rbase = wv * 8 + (lane >> 3);
    const int corig = (lane & 7) ^ (lane >> 3);
    const unsigned short* Asrc = A + (size_t)(bm + rbase) * Dd + corig * 8;
    const unsigned short* Bsrc = W + (size_t)(bn + rbase) * Dd + corig * 8;
    const int ldsb = wv * 1024;
    const int xk = (lr & 7);

    int kstep = kstep0;
    for (int it = 0; it < 16; ++it) {
        const int k0 = kstep * 64;
#pragma unroll
        for (int p = 0; p < 4; ++p) {
            gld16(Asrc + (size_t)(p * 32) * Dd + k0, lA + p * 4096 + ldsb);
            gld16(Bsrc + (size_t)(p * 32) * Dd + k0, lB + p * 4096 + ldsb);
        }
        __syncthreads();
#pragma unroll
        for (int s = 0; s < 2; ++s) {
            s16x8 af[4], bf[4];
#pragma unroll
            for (int m = 0; m < 4; ++m)
                af[m] = *(const s16x8*)(lA + (wr * 64 + m * 16 + lr) * 128 + (((s * 4 + g) ^ xk) << 4));
#pragma unroll
            for (int n = 0; n < 4; ++n)
                bf[n] = *(const s16x8*)(lB + (wc * 64 + n * 16 + lr) * 128 + (((s * 4 + g) ^ xk) << 4));
#pragma unroll
            for (int m = 0; m < 4; ++m)
#pragma unroll
                for (int n = 0; n < 4; ++n)
                    acc[m][n] = __builtin_amdgcn_mfma_f32_16x16x32_bf16(af[m], bf[n], acc[m][n], 0, 0, 0);
        }
        __syncthreads();
        kstep = (kstep + 1) & 15;
    }
}

// ---------------- QKV GEMM: z=0 Q row-major (pre-scaled); z=1 K chunk-swizzled; z=2 V^T chunk-swizzled ----------------
__global__ __launch_bounds__(256, 4) void gemm_qkv_k(const unsigned short* __restrict__ xb,
                                                     const unsigned short* __restrict__ Wqb,
                                                     const unsigned short* __restrict__ Wkb,
                                                     const unsigned short* __restrict__ Wvb,
                                                     const float* __restrict__ bq,
                                                     const float* __restrict__ bk,
                                                     const float* __restrict__ bv,
                                                     const int* __restrict__ lengths,
                                                     unsigned short* __restrict__ Qo,
                                                     unsigned short* __restrict__ Ko,
                                                     unsigned short* __restrict__ Vo) {
    __shared__ __align__(16) char lA[128 * 64 * 2];
    __shared__ __align__(16) char lB[128 * 64 * 2];
    const int z = blockIdx.z;
    const int bm = blockIdx.x * 128, bn = blockIdx.y * 128;
    if (z != 0 && (bm & 1023) >= lengths[bm >> 10]) return;  // fully padded K/V block

    const unsigned short* W = (z == 0) ? Wqb : (z == 1) ? Wkb : Wvb;
    const float* bias = (z == 0) ? bq : (z == 1) ? bk : bv;

    const int tid = threadIdx.x;
    const int wv = tid >> 6, lane = tid & 63, g = lane >> 4, lr = lane & 15;
    const int wr = wv >> 1, wc = wv & 1;
    const int kstep0 = (blockIdx.x * 5 + blockIdx.y * 3 + z * 7) & 15;

    f32x4 acc[4][4];
#pragma unroll
    for (int m = 0; m < 4; ++m)
#pragma unroll
        for (int n = 0; n < 4; ++n) acc[m][n] = (f32x4){0.f, 0.f, 0.f, 0.f};

    gemm_kloop(xb, W, lA, lB, bm, bn, tid, kstep0, acc);

    const int row0 = bm + wr * 64 + g * 4;
    if (z == 0) {
        const float qs = 0.125f * 1.44269504f;  // dk^-0.5 * log2(e)
#pragma unroll
        for (int m = 0; m < 4; ++m)
#pragma unroll
            for (int n = 0; n < 4; ++n) {
                const int col = bn + wc * 64 + n * 16 + lr;
                const float bv_ = bias[col];
#pragma unroll
                for (int r = 0; r < 4; ++r)
                    Qo[(size_t)(row0 + m * 16 + r) * Dd + col] = f2bf((acc[m][n][r] + bv_) * qs);
            }
    } else if (z == 1) {
        // Kg[((b*H+h)*N + tok)*64 + ((dk>>3)^(tok&7))*8 + (dk&7)]
#pragma unroll
        for (int m = 0; m < 4; ++m)
#pragma unroll
            for (int n = 0; n < 4; ++n) {
                const int col = bn + wc * 64 + n * 16 + lr;
                const int h = col >> 6, dk = col & 63;
                const float bv_ = bias[col];
#pragma unroll
                for (int r = 0; r < 4; ++r) {
                    const int rowg = row0 + m * 16 + r;
                    const int b_ = rowg >> 10, tok = rowg & 1023;
                    size_t idx = ((size_t)(b_ * Hh + h) * Nn + tok) * DKk +
                                 (((dk >> 3) ^ (tok & 7)) << 3) + (dk & 7);
                    Ko[idx] = f2bf(acc[m][n][r] + bv_);
                }
            }
    } else {
        // Vt[((b*H+h)*64 + dk)*N + (tok&~63) + (((tok>>3)&7)^(dk&7))*8 + (tok&7)]
#pragma unroll
        for (int m = 0; m < 4; ++m)
#pragma unroll
            for (int n = 0; n < 4; ++n) {
                const int col = bn + wc * 64 + n * 16 + lr;
                const int h = col >> 6, dk = col & 63;
                const float bv_ = bias[col];
                const int rowg = row0 + m * 16;
                const int b_ = rowg >> 10, tok = rowg & 1023;
                u16x4 t;
#pragma unroll
                for (int r = 0; r < 4; ++r) t[r] = f2bf(acc[m][n][r] + bv_);
                size_t idx = ((size_t)(b_ * Hh + h) * DKk + dk) * Nn + (tok & ~63) +
                             ((((tok >> 3) & 7) ^ (dk & 7)) << 3) + (tok & 7);
                *(u16x4*)(Vo + idx) = t;
            }
    }
}

// ---------------- out projection GEMM: 64x128 tile (512 blocks = 2/CU), BK=64 ----------------
// Wave tile 32x64 (wr=wv>>1, wc=wv&1), acc[2][4]. Same XOR staging/read map.
__global__ __launch_bounds__(256, 4) void gemm_out_k(const unsigned short* __restrict__ Ab,
                                                     const unsigned short* __restrict__ Wob,
                                                     const float* __restrict__ bo,
                                                     float* __restrict__ out) {
    __shared__ __align__(16) char lA[64 * 64 * 2];
    __shared__ __align__(16) char lB[128 * 64 * 2];
    const int tid = threadIdx.x;
    const int wv = tid >> 6, lane = tid & 63, g = lane >> 4, lr = lane & 15;
    const int wr = wv >> 1, wc = wv & 1;
    const int bm = blockIdx.x * 64, bn = blockIdx.y * 128;
    const int kstep0 = (blockIdx.x * 5 + blockIdx.y * 3) & 15;

    f32x4 acc[2][4];
#pragma unroll
    for (int m = 0; m < 2; ++m)
#pragma unroll
        for (int n = 0; n < 4; ++n) acc[m][n] = (f32x4){0.f, 0.f, 0.f, 0.f};

    const int rbase = wv * 8 + (lane >> 3);
    const int corig = (lane & 7) ^ (lane >> 3);
    const unsigned short* Asrc = Ab + (size_t)(bm + rbase) * Dd + corig * 8;
    const unsigned short* Bsrc = Wob + (size_t)(bn + rbase) * Dd + corig * 8;
    const int ldsb = wv * 1024;
    const int xk = (lr & 7);

    int kstep = kstep0;
    for (int it = 0; it < 16; ++it) {
        const int k0 = kstep * 64;
#pragma unroll
        for (int p = 0; p < 2; ++p)
            gld16(Asrc + (size_t)(p * 32) * Dd + k0, lA + p * 4096 + ldsb);
#pragma unroll
        for (int p = 0; p < 4; ++p)
            gld16(Bsrc + (size_t)(p * 32) * Dd + k0, lB + p * 4096 + ldsb);
        __syncthreads();
#pragma unroll
        for (int s = 0; s < 2; ++s) {
            s16x8 af[2], bf[4];
#pragma unroll
            for (int m = 0; m < 2; ++m)
                af[m] = *(const s16x8*)(lA + (wr * 32 + m * 16 + lr) * 128 + (((s * 4 + g) ^ xk) << 4));
#pragma unroll
            for (int n = 0; n < 4; ++n)
                bf[n] = *(const s16x8*)(lB + (wc * 64 + n * 16 + lr) * 128 + (((s * 4 + g) ^ xk) << 4));
#pragma unroll
            for (int m = 0; m < 2; ++m)
#pragma unroll
                for (int n = 0; n < 4; ++n)
                    acc[m][n] = __builtin_amdgcn_mfma_f32_16x16x32_bf16(af[m], bf[n], acc[m][n], 0, 0, 0);
        }
        __syncthreads();
        kstep = (kstep + 1) & 15;
    }

    const int row0 = bm + wr * 32 + g * 4;
#pragma unroll
    for (int m = 0; m < 2; ++m)
#pragma unroll
        for (int n = 0; n < 4; ++n) {
            const int col = bn + wc * 64 + n * 16 + lr;
            const float bv_ = bo[col];
#pragma unroll
            for (int r = 0; r < 4; ++r)
                out[(size_t)(row0 + m * 16 + r) * Dd + col] = acc[m][n][r] + bv_;
        }
}

// ---------------- fused attention: QBLK=128 (8 waves), swapped QK^T, acc-bias log2 softmax ----------------
__global__ __launch_bounds__(512) void attn_k(const unsigned short* __restrict__ Q,
                                              const unsigned short* __restrict__ Kg,
                                              const unsigned short* __restrict__ Vtg,
                                              const int* __restrict__ lengths,
                                              unsigned short* __restrict__ O) {
    const int tid = threadIdx.x;
    const int wv = tid >> 6, lane = tid & 63, g = lane >> 4, lr = lane & 15;
    const int bid = blockIdx.x;
    const int qt = bid & 7, h = (bid >> 3) & 15, b = bid >> 7;
    const int len = lengths[b];
    const int nt = (len + 63) >> 6;

    __shared__ __align__(16) char Ks[2 * 64 * 128];    // [buf][key][dk], swizzled chunks
    __shared__ __align__(16) char Vs[2 * 64 * 128];    // [buf][dk][key], swizzled chunks
    __shared__ __align__(16) char Ps[8][16 * 128];     // per-wave P [q][key], swizzled chunks

    s16x8 qf[2];
    {
        const int qrow = b * Nn + qt * 128 + wv * 16 + lr;
        const unsigned short* qp = Q + (size_t)qrow * Dd + h * DKk + g * 8;
        qf[0] = *(const s16x8*)qp;
        qf[1] = *(const s16x8*)(qp + 32);
    }

    float m_run = 0.f, l_run = 0.f;
    f32x4 oacc[4];
#pragma unroll
    for (int dt = 0; dt < 4; ++dt) oacc[dt] = (f32x4){0.f, 0.f, 0.f, 0.f};

    const int r0 = tid >> 3, c0 = tid & 7;   // 512 threads cover all 512 chunks/matrix
    const unsigned short* Kbase = Kg + (size_t)(b * Hh + h) * Nn * DKk;
    const unsigned short* Vbase = Vtg + (size_t)(b * Hh + h) * DKk * Nn;

    const int xk16 = (lr & 7) << 4;
    const int shsrc = (lane & 48) | (g * 4);

    // prologue: stage tile 0 into buf 0
    gld16(Kbase + (size_t)r0 * DKk + c0 * 8, Ks + tid * 16);
    gld16(Vbase + (size_t)r0 * Nn + c0 * 8, Vs + tid * 16);

    int cur = 0;
    for (int kt = 0; kt < nt; ++kt) {
        const int kb = kt * 64;
        {
            const int kb2 = (kt + 1 < nt) ? kb + 64 : 0;
            const int nb = (cur ^ 1) * 8192;
            gld16(Kbase + (size_t)(kb2 + r0) * DKk + c0 * 8, Ks + nb + tid * 16);
            gld16(Vbase + (size_t)r0 * Nn + kb2 + c0 * 8, Vs + nb + tid * 16);
        }
        wait_vm2_barrier();  // tile kt resident; tile kt+1's loads stay in flight

        const char* ks_ = Ks + cur * 8192;
        const char* vs_ = Vs + cur * 8192;

        const float nm = -m_run;
        f32x4 sfr[4];
        __builtin_amdgcn_s_setprio(1);
#pragma unroll
        for (int ct = 0; ct < 4; ++ct) {
            f32x4 c = (f32x4){nm, nm, nm, nm};
#pragma unroll
            for (int s = 0; s < 2; ++s) {
                s16x8 kf = *(const s16x8*)(ks_ + (ct * 16 + lr) * 128 + ((((s * 4 + g) << 4)) ^ xk16));
                c = __builtin_amdgcn_mfma_f32_16x16x32_bf16(kf, qf[s], c, 0, 0, 0);
            }
            sfr[ct] = c;
        }
        __builtin_amdgcn_s_setprio(0);

        float mx = -INFINITY;
        if (kb + 64 <= len) {
#pragma unroll
            for (int ct = 0; ct < 4; ++ct)
#pragma unroll
                for (int r = 0; r < 4; ++r) mx = fmaxf(mx, sfr[ct][r]);
        } else {
#pragma unroll
            for (int ct = 0; ct < 4; ++ct) {
                const int kb4 = kb + ct * 16 + g * 4;
#pragma unroll
                for (int r = 0; r < 4; ++r) {
                    const float s_ = (kb4 + r < len) ? sfr[ct][r] : -INFINITY;
                    sfr[ct][r] = s_;
                    mx = fmaxf(mx, s_);
                }
            }
        }
        mx = fmaxf(mx, __shfl_xor(mx, 16));
        mx = fmaxf(mx, __shfl_xor(mx, 32));

        float ls = 0.f;
        if (__any(mx > 8.f)) {
            const float dm = fmaxf(mx, 0.f);
            const float alpha = fexp2(-dm);
            m_run += dm;
            l_run *= alpha;
            float ao[4];
#pragma unroll
            for (int r = 0; r < 4; ++r) ao[r] = __shfl(alpha, shsrc + r);
#pragma unroll
            for (int dt = 0; dt < 4; ++dt)
#pragma unroll
                for (int r = 0; r < 4; ++r) oacc[dt][r] *= ao[r];
#pragma unroll
            for (int ct = 0; ct < 4; ++ct)
#pragma unroll
                for (int r = 0; r < 4; ++r) {
                    const float p = fexp2(sfr[ct][r] - dm);
                    sfr[ct][r] = p;
                    ls += p;
                }
        } else {
#pragma unroll
            for (int ct = 0; ct < 4; ++ct)
#pragma unroll
                for (int r = 0; r < 4; ++r) {
                    const float p = fexp2(sfr[ct][r]);
                    sfr[ct][r] = p;
                    ls += p;
                }
        }
        ls += __shfl_xor(ls, 16);
        ls += __shfl_xor(ls, 32);
        l_run += ls;

#pragma unroll
        for (int ct = 0; ct < 4; ++ct) {
            unsigned int w0, w1;
            asm("v_cvt_pk_bf16_f32 %0, %1, %2" : "=v"(w0) : "v"(sfr[ct][0]), "v"(sfr[ct][1]));
            asm("v_cvt_pk_bf16_f32 %0, %1, %2" : "=v"(w1) : "v"(sfr[ct][2]), "v"(sfr[ct][3]));
            u32x2 wp; wp[0] = w0; wp[1] = w1;
            *(u32x2*)(Ps[wv] + lr * 128 + ((ct * 32 + g * 8) ^ xk16)) = wp;
        }

        __builtin_amdgcn_s_setprio(1);
#pragma unroll
        for (int s = 0; s < 2; ++s) {
            s16x8 pf = *(const s16x8*)(Ps[wv] + lr * 128 + ((((s * 4 + g) << 4)) ^ xk16));
#pragma unroll
            for (int dt = 0; dt < 4; ++dt) {
                s16x8 vf = *(const s16x8*)(vs_ + (dt * 16 + lr) * 128 + ((((s * 4 + g) << 4)) ^ xk16));
                oacc[dt] = __builtin_amdgcn_mfma_f32_16x16x32_bf16(pf, vf, oacc[dt], 0, 0, 0);
            }
        }
        __builtin_amdgcn_s_setprio(0);
        __builtin_amdgcn_s_barrier();
        cur ^= 1;
    }

    float lo[4];
#pragma unroll
    for (int r = 0; r < 4; ++r) lo[r] = __shfl(l_run, shsrc + r);
#pragma unroll
    for (int dt = 0; dt < 4; ++dt) {
        const int col = h * DKk + dt * 16 + lr;
#pragma unroll
        for (int r = 0; r < 4; ++r) {
            const int row = qt * 128 + wv * 16 + g * 4 + r;
            float v = oacc[dt][r] / lo[r];
            O[(size_t)(b * Nn + row) * Dd + col] = f2bf(v);
        }
    }
}

extern "C" void kernel_launch(void* const* d_in, const int* in_sizes, int n_in,
                              void* d_out, int out_size, void* d_ws, size_t ws_size,
                              hipStream_t stream) {
    const float* x  = (const float*)d_in[0];
    const unsigned int* mraw = (const unsigned int*)d_in[1];
    const float* Wq = (const float*)d_in[2];
    const float* bq = (const float*)d_in[3];
    const float* Wk = (const float*)d_in[4];
    const float* bk = (const float*)d_in[5];
    const float* Wv = (const float*)d_in[6];
    const float* bv = (const float*)d_in[7];
    const float* Wo = (const float*)d_in[8];
    const float* bo = (const float*)d_in[9];

    char* ws = (char*)d_ws;
    int* lengths        = (int*)ws;                      ws += 1 << 16;
    unsigned short* xb  = (unsigned short*)ws;           ws += (size_t)Bb * Nn * Dd * 2;
    unsigned short* Wqb = (unsigned short*)ws;           ws += (size_t)Dd * Dd * 2;
    unsigned short* Wkb = (unsigned short*)ws;           ws += (size_t)Dd * Dd * 2;
    unsigned short* Wvb = (unsigned short*)ws;           ws += (size_t)Dd * Dd * 2;
    unsigned short* Wob = (unsigned short*)ws;           ws += (size_t)Dd * Dd * 2;
    unsigned short* Qb  = (unsigned short*)ws;           ws += (size_t)Bb * Nn * Dd * 2;
    unsigned short* Kg  = (unsigned short*)ws;           ws += (size_t)Bb * Nn * Dd * 2;
    unsigned short* Vtg = (unsigned short*)ws;           ws += (size_t)Bb * Nn * Dd * 2;
    unsigned short* Ab  = (unsigned short*)ws;

    cast_k<<<4097, 256, 0, stream>>>(x, Wq, Wk, Wv, Wo, mraw,
                                     xb, Wqb, Wkb, Wvb, Wob, lengths);

    dim3 qkv_grid(Bb * Nn / 128, Dd / 128, 3);
    gemm_qkv_k<<<qkv_grid, 256, 0, stream>>>(xb, Wqb, Wkb, Wvb, bq, bk, bv, lengths,
                                             Qb, Kg, Vtg);

    attn_k<<<Bb * Hh * (Nn / 128), 512, 0, stream>>>(Qb, Kg, Vtg, lengths, Ab);

    dim3 out_grid(Bb * Nn / 64, Dd / 128);
    gemm_out_k<<<out_grid, 256, 0, stream>>>(Ab, Wob, bo, (float*)d_out);
}